// Round 3
// baseline (191.963 us; speedup 1.0000x reference)
//
#include <hip/hip_runtime.h>
#include <cstdint>
#include <cstddef>
#include <type_traits>

#define B_ROWS 16384
#define D_DIM  512
#define O_DIM  512
#define K_DIM  4608    // 9 * 512: f=0 silu (base), f=1..8 spline channels
#define BM 128
#define BN 256
#define BK 32

typedef __bf16 bf16;
typedef __attribute__((ext_vector_type(8))) bf16  bf16x8;
typedef __attribute__((ext_vector_type(4))) float f32x4;

__device__ __forceinline__ void async_load16(const void* g, void* l) {
    __builtin_amdgcn_global_load_lds(
        (const __attribute__((address_space(1))) void*)g,
        (__attribute__((address_space(3))) void*)l,
        16, 0, 0);
}

__device__ __forceinline__ uint32_t pk2(float a, float b) {
    uint16_t ua = __builtin_bit_cast(uint16_t, (__bf16)a);
    uint16_t ub = __builtin_bit_cast(uint16_t, (__bf16)b);
    return (uint32_t)ua | ((uint32_t)ub << 16);
}

// Spline channels b0..b7 for one element as 4 packed bf16 pair-regs.
__device__ __forceinline__ void spline_pairs(float xv, uint32_t out[4]) {
    float xn = fminf(fmaxf(xv, -2.0f), 2.0f);
    float t  = (xn + 3.2f) * 2.5f;        // in [3,13]
    int   j0 = (int)t;                    // t>0 so trunc==floor
    float u  = t - (float)j0;
    float u2 = u * u, u3 = u2 * u, omu = 1.0f - u;
    const float s6 = 1.0f / 6.0f;
    float w0 = omu * omu * omu * s6;
    float w1 = (3.0f * u3 - 6.0f * u2 + 4.0f) * s6;
    float w2 = (-3.0f * u3 + 3.0f * u2 + 3.0f * u + 1.0f) * s6;
    float w3 = u3 * s6;
    uint64_t W64 = ((uint64_t)pk2(w2, w3) << 32) | pk2(w0, w1);
    int sh = (j0 - 3) * 16;               // 0..160
    uint64_t lo = W64 << (sh & 63);
    uint64_t hi = W64 >> ((64 - sh) & 63);
    uint32_t lo_lo = (uint32_t)lo, lo_hi = (uint32_t)(lo >> 32);
    uint32_t hi_lo = (uint32_t)hi, hi_hi = (uint32_t)(hi >> 32);
    bool lt64 = sh < 64, eq0 = (sh == 0), lt128 = sh < 128;
    out[0] = lt64 ? lo_lo : 0u;
    out[1] = lt64 ? lo_hi : 0u;
    out[2] = lt64 ? (eq0 ? 0u : hi_lo) : (lt128 ? lo_lo : 0u);
    out[3] = lt64 ? (eq0 ? 0u : hi_hi) : (lt128 ? lo_hi : 0u);
}

// base_weight[O,D] + spline_weight[O,D,8] fp32 -> W[O, 4608] bf16, k = f*512 + i
__global__ void pack_w_kernel(const float* __restrict__ bw,
                              const float* __restrict__ sw,
                              bf16* __restrict__ W) {
    int idx = blockIdx.x * blockDim.x + threadIdx.x;   // over O*64
    if (idx >= O_DIM * 64) return;
    int o  = idx >> 6;
    int i0 = (idx & 63) * 8;

    bf16 ob[9][8];
    const float* bwp = bw + (size_t)o * D_DIM + i0;
#pragma unroll
    for (int e = 0; e < 8; e++) {
        ob[0][e] = (bf16)bwp[e];
        const float* sp = sw + ((size_t)o * D_DIM + i0 + e) * 8;
#pragma unroll
        for (int c = 0; c < 8; c++)
            ob[c + 1][e] = (bf16)sp[c];
    }
    bf16* row = W + (size_t)o * K_DIM + i0;
#pragma unroll
    for (int f = 0; f < 9; f++)
        *(bf16x8*)(row + (size_t)f * D_DIM) = *(const bf16x8*)ob[f];
}

// counted-vmcnt barrier (writer-side lgkm drain BEFORE barrier entry)
#define BARW(n) asm volatile("s_waitcnt vmcnt(" #n ") lgkmcnt(0)\n\ts_barrier" ::: "memory")

// R12: m201 phase discipline on top of R11's buffering. Each step is one
// phase: {x-pref | B stage t+4 | 8 ds_reads | featurize | As write} ->
// s_barrier -> lgkmcnt(0) -> setprio(1) -> 16 MFMA -> setprio(0) ->
// end-barrier (counted-vmcnt BARW on odd t, plain s_barrier on even t).
// The barrier PAIR around the MFMA cluster is m201's proven lever (T3):
// all waves' ds_reads are issued before any wave enters MFMA, so the LDS
// pipe drains all reads while MFMA clusters run, instead of each wave
// serially eating its own ds_read latency. Buffers/staging/vmcnt as R11:
// Bs 6-deep (stage distance 4), As 4-deep (write distance 2); k-order and
// MFMA sequence unchanged -> bitwise-identical accumulation.
__global__ __launch_bounds__(512, 2)
void gemm_fused_kernel(const float* __restrict__ x, const bf16* __restrict__ W,
                       float* __restrict__ C) {
    __shared__ __align__(16) bf16 As0[BM * BK], As1[BM * BK], As2[BM * BK], As3[BM * BK]; // 4x8KB
    __shared__ __align__(16) bf16 Bs0[BN * BK], Bs1[BN * BK], Bs2[BN * BK];               // 6x16KB
    __shared__ __align__(16) bf16 Bs3[BN * BK], Bs4[BN * BK], Bs5[BN * BK];

    const int tid  = threadIdx.x;
    const int bid  = blockIdx.x;
    // n-tile = bid&1: round-robin XCD dispatch -> each XCD one 2.36MB W-panel
    const int n0   = (bid & 1) * BN;
    const int m0   = (bid >> 1) * BM;
    const int wave = tid >> 6;
    const int lane = tid & 63;
    const int wm   = (wave >> 2) * 64;   // 0 or 64
    const int wn   = (wave & 3) * 64;    // 0,64,128,192
    const int l15  = lane & 15;
    const int quad = lane >> 4;
    const int swz  = (l15 >> 1) & 3;
    const int aoff = l15 * BK + (quad ^ swz) * 8;
    const int boff = (wn + l15) * BK + (quad ^ swz) * 8;

    const int rA = tid >> 2;             // 0..127
    const int q8 = tid & 3;
    const float* xrow = x + (size_t)(m0 + rA) * D_DIM + q8 * 8;
    const int awo = rA * BK + ((q8 ^ ((rA >> 1) & 3)) * 8);   // XOR slot swizzle

    // Bs staging: linear dest, source col pre-swizzled to match boff
    const bf16* gB = W + (size_t)(n0 + (tid >> 2)) * K_DIM
                       + (((tid & 3) ^ ((tid >> 3) & 3)) * 8);

    bf16* const AsArr[4] = {As0, As1, As2, As3};
    bf16* const BsArr[6] = {Bs0, Bs1, Bs2, Bs3, Bs4, Bs5};

    f32x4 acc[4][4] = {};
    uint32_t vpk[2][4][8];   // [chunk parity][channel-pair][element]
    float xe[8];

    auto write_pack = [&](bf16* slab, const uint32_t (&P)[4][8], int j) {
        const int pr = j >> 1;
        uint32_t o[4];
#pragma unroll
        for (int m = 0; m < 4; m++) {
            uint32_t lo = P[pr][2*m], hi = P[pr][2*m+1];
            o[m] = (j & 1) ? ((lo >> 16) | (hi & 0xFFFF0000u))
                           : ((lo & 0xFFFFu) | (hi << 16));
        }
        *(uint4*)(slab + awo) = *(const uint4*)o;
    };
    auto write_silu = [&](bf16* slab) {
        float sl[8];
#pragma unroll
        for (int e = 0; e < 8; e++)
            sl[e] = xe[e] * __builtin_amdgcn_rcpf(1.0f + __expf(-xe[e]));
        uint32_t o[4] = {pk2(sl[0],sl[1]), pk2(sl[2],sl[3]),
                         pk2(sl[4],sl[5]), pk2(sl[6],sl[7])};
        *(uint4*)(slab + awo) = *(const uint4*)o;
    };

    // ---- prologue: x chunk0; stage steps 0..3; features c0; As slabs 0,1 ----
    {
        float4 a = *(const float4*)xrow;
        float4 b = *(const float4*)(xrow + 4);
        xe[0]=a.x; xe[1]=a.y; xe[2]=a.z; xe[3]=a.w;
        xe[4]=b.x; xe[5]=b.y; xe[6]=b.z; xe[7]=b.w;
#pragma unroll
        for (int F = 0; F < 4; F++) {   // step F buffer = F (c=0)
            const bf16* src = gB + (size_t)(F * 512);
            async_load16(src,                       BsArr[F] + tid * 8);
            async_load16(src + (size_t)128 * K_DIM, BsArr[F] + tid * 8 + 4096);
        }
#pragma unroll
        for (int e = 0; e < 8; e++) {
            uint32_t o4[4];
            spline_pairs(xe[e], o4);
            vpk[0][0][e]=o4[0]; vpk[0][1][e]=o4[1];
            vpk[0][2][e]=o4[2]; vpk[0][3][e]=o4[3];
        }
        write_silu(As0);              // step 0 = (c0, f0) silu
        write_pack(As1, vpk[0], 0);   // step 1 = (c0, f1) spline channel 0
        BARW(4);   // retire stages for steps 0,1; keep 2,3 in flight
    }

    auto step_body = [&](auto c4v, auto fv, int c) {
        constexpr int C4 = decltype(c4v)::value;   // c mod 4
        constexpr int F  = decltype(fv)::value;    // 0..8
        constexpr int PC = C4 & 1;
        constexpr int BR = (3 * PC + F) % 6;       // Bs read  = t mod 6
        constexpr int BW = (3 * PC + F + 4) % 6;   // Bs stage = (t+4) mod 6
        constexpr int AR = (C4 + F) & 3;           // As read  = t mod 4
        constexpr int AW = (C4 + F + 2) & 3;       // As write = (t+2) mod 4

        // (0) x prefetch for chunk c+1 (before B stages -> older in FIFO)
        if (F == 0 && c < 15) {
            float4 a = *(const float4*)(xrow + (c + 1) * 32);
            float4 b = *(const float4*)(xrow + (c + 1) * 32 + 4);
            xe[0]=a.x; xe[1]=a.y; xe[2]=a.z; xe[3]=a.w;
            xe[4]=b.x; xe[5]=b.y; xe[6]=b.z; xe[7]=b.w;
        }
        // (1) B stage for step t+4
        {
            constexpr int f2 = (F + 4 <= 8) ? (F + 4) : (F - 5);
            const int c2 = (F + 4 <= 8) ? c : (c + 1);
            if (c2 < 16) {
                const bf16* src = gB + (size_t)(f2 * 512 + c2 * 32);
                async_load16(src,                       BsArr[BW] + tid * 8);
                async_load16(src + (size_t)128 * K_DIM, BsArr[BW] + tid * 8 + 4096);
            }
        }
        // (2) current-step fragment reads
        bf16x8 af[4], bfr[4];
#pragma unroll
        for (int tt = 0; tt < 4; tt++)
            af[tt] = *(const bf16x8*)(AsArr[AR] + (wm + tt * 16) * BK + aoff);
#pragma unroll
        for (int tt = 0; tt < 4; tt++)
            bfr[tt] = *(const bf16x8*)(BsArr[BR] + boff + tt * 16 * BK);

        // (3) pipelined featurize: elem F-1 of chunk c+1 (VALU hides ds_read)
        if (F >= 1 && c < 15) {
            uint32_t o4[4];
            spline_pairs(xe[F - 1], o4);
            vpk[PC ^ 1][0][F-1]=o4[0]; vpk[PC ^ 1][1][F-1]=o4[1];
            vpk[PC ^ 1][2][F-1]=o4[2]; vpk[PC ^ 1][3][F-1]=o4[3];
        }
        // (4) As write for step t+2
        if constexpr (F <= 6) {
            write_pack(AsArr[AW], vpk[PC], F + 1);          // (c, F+2) -> j=F+1
        } else if constexpr (F == 7) {
            if (c < 15) write_silu(AsArr[AW]);              // (c+1, 0) silu
        } else {
            if (c < 15) write_pack(AsArr[AW], vpk[PC ^ 1], 0); // (c+1, 1) -> j=0
        }

        // (5) phase barrier pair (m201/T3): all waves' reads issued before
        // any MFMA starts; per-wave lgkm drain after the barrier.
        __builtin_amdgcn_s_barrier();
        asm volatile("s_waitcnt lgkmcnt(0)" ::: "memory");
        __builtin_amdgcn_sched_barrier(0);
        __builtin_amdgcn_s_setprio(1);
#pragma unroll
        for (int im = 0; im < 4; im++)
#pragma unroll
            for (int jn = 0; jn < 4; jn++)
                acc[im][jn] = __builtin_amdgcn_mfma_f32_16x16x32_bf16(
                    af[im], bfr[jn], acc[im][jn], 0, 0, 0);
        __builtin_amdgcn_s_setprio(0);

        // (6) phase-end barrier. Counted vmcnt at interval (odd-t) ends,
        // plain s_barrier on even-t phase ends.
        if constexpr (((PC + F) & 1) == 1) {
            if constexpr (PC == 0 && F == 1) {
                BARW(6);                       // interval held x(c+1) + 4 stages
            } else if constexpr (PC == 1 && F == 0) {
                if (c < 15) { BARW(6); } else { BARW(4); }
            } else if constexpr (F == 8) {
                if (c != 15) BARW(4);          // (15,8): final step, no barrier
            } else if constexpr (F == 6) {
                if (c == 15) { BARW(0); } else { BARW(4); }  // tail: no stages left in range
            } else {
                BARW(4);
            }
        } else {
            __builtin_amdgcn_s_barrier();
        }
    };

#define IC(n) std::integral_constant<int,(n)>{}
    auto chunk_body = [&](auto c4v, int c) {
        step_body(c4v, IC(0), c); step_body(c4v, IC(1), c); step_body(c4v, IC(2), c);
        step_body(c4v, IC(3), c); step_body(c4v, IC(4), c); step_body(c4v, IC(5), c);
        step_body(c4v, IC(6), c); step_body(c4v, IC(7), c); step_body(c4v, IC(8), c);
    };

    for (int cc = 0; cc < 16; cc += 4) {
        chunk_body(IC(0), cc);
        chunk_body(IC(1), cc + 1);
        chunk_body(IC(2), cc + 2);
        chunk_body(IC(3), cc + 3);
    }
#undef IC

    // C/D layout: col = lane&15, row = quad*4 + reg   [measured m89/m91]
#pragma unroll
    for (int im = 0; im < 4; im++) {
        const int rbase = m0 + wm + im * 16 + quad * 4;
#pragma unroll
        for (int jn = 0; jn < 4; jn++) {
            const int col = n0 + wn + jn * 16 + l15;
#pragma unroll
            for (int rr = 0; rr < 4; rr++)
                C[(size_t)(rbase + rr) * O_DIM + col] = acc[im][jn][rr];
        }
    }
}

extern "C" void kernel_launch(void* const* d_in, const int* in_sizes, int n_in,
                              void* d_out, int out_size, void* d_ws, size_t ws_size,
                              hipStream_t stream) {
    const float* x  = (const float*)d_in[0];
    const float* bw = (const float*)d_in[1];
    const float* sw = (const float*)d_in[2];
    float* out = (float*)d_out;

    const size_t Wbytes = (size_t)O_DIM * K_DIM * sizeof(bf16);  // 4.7 MB
    if (ws_size < Wbytes) return;
    bf16* W = (bf16*)d_ws;

    pack_w_kernel<<<(O_DIM * 64 + 255) / 256, 256, 0, stream>>>(bw, sw, W);
    gemm_fused_kernel<<<dim3(B_ROWS / BM * (O_DIM / BN)), dim3(512), 0, stream>>>(x, W, out);
}

// Round 4
// 167.910 us; speedup vs baseline: 1.1433x; 1.1433x over previous
//
#include <hip/hip_runtime.h>
#include <cstdint>
#include <cstddef>
#include <type_traits>

#define B_ROWS 16384
#define D_DIM  512
#define O_DIM  512
#define BM 128
#define BN 256
#define BK 32
// W is repacked fragment-major: Wf[tIdx=f*16+c][cb=o/16][lane][8 bf16]
// (tIdx<144, cb<32, lane<64). A wave's B-fragment (16 cols x 8 k) is the
// contiguous 1KB chunk at ((tIdx*32+cb)*64)*8 -- one coalesced
// global_load_dwordx4 per lane, straight to VGPR. Same bytes as before,
// bitwise-identical MFMA operands (lane k-block = quad).

typedef __bf16 bf16;
typedef __attribute__((ext_vector_type(8))) bf16  bf16x8;
typedef __attribute__((ext_vector_type(4))) float f32x4;

__device__ __forceinline__ uint32_t pk2(float a, float b) {
    uint16_t ua = __builtin_bit_cast(uint16_t, (__bf16)a);
    uint16_t ub = __builtin_bit_cast(uint16_t, (__bf16)b);
    return (uint32_t)ua | ((uint32_t)ub << 16);
}

// Spline channels b0..b7 for one element as 4 packed bf16 pair-regs.
__device__ __forceinline__ void spline_pairs(float xv, uint32_t out[4]) {
    float xn = fminf(fmaxf(xv, -2.0f), 2.0f);
    float t  = (xn + 3.2f) * 2.5f;        // in [3,13]
    int   j0 = (int)t;                    // t>0 so trunc==floor
    float u  = t - (float)j0;
    float u2 = u * u, u3 = u2 * u, omu = 1.0f - u;
    const float s6 = 1.0f / 6.0f;
    float w0 = omu * omu * omu * s6;
    float w1 = (3.0f * u3 - 6.0f * u2 + 4.0f) * s6;
    float w2 = (-3.0f * u3 + 3.0f * u2 + 3.0f * u + 1.0f) * s6;
    float w3 = u3 * s6;
    uint64_t W64 = ((uint64_t)pk2(w2, w3) << 32) | pk2(w0, w1);
    int sh = (j0 - 3) * 16;               // 0..160
    uint64_t lo = W64 << (sh & 63);
    uint64_t hi = W64 >> ((64 - sh) & 63);
    uint32_t lo_lo = (uint32_t)lo, lo_hi = (uint32_t)(lo >> 32);
    uint32_t hi_lo = (uint32_t)hi, hi_hi = (uint32_t)(hi >> 32);
    bool lt64 = sh < 64, eq0 = (sh == 0), lt128 = sh < 128;
    out[0] = lt64 ? lo_lo : 0u;
    out[1] = lt64 ? lo_hi : 0u;
    out[2] = lt64 ? (eq0 ? 0u : hi_lo) : (lt128 ? lo_lo : 0u);
    out[3] = lt64 ? (eq0 ? 0u : hi_hi) : (lt128 ? lo_hi : 0u);
}

// base_weight[O,D] + spline_weight[O,D,8] fp32 -> frag-major Wf (bf16).
// Thread (o, i0): computes 9 channels x 8 i; channel f's chunk lands at
// tIdx = f*16 + i0/32, cb = o/16, lane = (o&15) + ((i0&31)/8)*16.
__global__ void pack_w_kernel(const float* __restrict__ bw,
                              const float* __restrict__ sw,
                              bf16* __restrict__ W) {
    int idx = blockIdx.x * blockDim.x + threadIdx.x;   // over O*64
    if (idx >= O_DIM * 64) return;
    int o  = idx >> 6;
    int i0 = (idx & 63) * 8;

    bf16 ob[9][8];
    const float* bwp = bw + (size_t)o * D_DIM + i0;
#pragma unroll
    for (int e = 0; e < 8; e++) {
        ob[0][e] = (bf16)bwp[e];
        const float* sp = sw + ((size_t)o * D_DIM + i0 + e) * 8;
#pragma unroll
        for (int c = 0; c < 8; c++)
            ob[c + 1][e] = (bf16)sp[c];
    }
    const int c   = i0 >> 5;              // k-chunk within channel
    const int sub = (i0 & 31) >> 3;       // quad (k-block within chunk)
    const int cb  = o >> 4;
    const int ln  = (o & 15) + sub * 16;
#pragma unroll
    for (int f = 0; f < 9; f++) {
        size_t off = ((size_t)((f * 16 + c) * 32 + cb) * 64 + ln) * 8;
        *(bf16x8*)(W + off) = *(const bf16x8*)ob[f];
    }
}

// As-only barrier: drain LDS ops, then barrier. No vmcnt drain anywhere --
// B-fragments live in private VGPRs now.
#define BARA asm volatile("s_waitcnt lgkmcnt(0)\n\ts_barrier" ::: "memory")

// R13: kill the B-side LDS round trip. R11's LDS pipe budget was 88KB/step
// per CU (1035 cyc @85B/cyc) -- the largest pipe, 59% of the step. B was
// 55% of it (32KB frag re-reads + 16KB gload_lds writes). Now B-frags load
// directly L2->VGPR from frag-major Wf (coalesced dwordx4), double-buffered
// brA/brB at distance 1 (~1 step ≈ 700cyc >> 200cyc L2 latency). LDS holds
// only As (4x8KB): 40KB/step. Barriers: R11's 2-step cadence, lgkm-only.
// MFMA operand bits and order identical to R11 -> same absmax.
__global__ __launch_bounds__(512, 2)
void gemm_fused_kernel(const float* __restrict__ x, const bf16* __restrict__ Wf,
                       float* __restrict__ C) {
    __shared__ __align__(16) bf16 As0[BM * BK], As1[BM * BK], As2[BM * BK], As3[BM * BK];

    const int tid  = threadIdx.x;
    const int bid  = blockIdx.x;
    // n-tile = bid&1: round-robin XCD dispatch -> each XCD one 2.36MB W-panel
    const int n0   = (bid & 1) * BN;
    const int m0   = (bid >> 1) * BM;
    const int wave = tid >> 6;
    const int lane = tid & 63;
    const int wm   = (wave >> 2) * 64;   // 0 or 64
    const int wn   = (wave & 3) * 64;    // 0,64,128,192
    const int l15  = lane & 15;
    const int quad = lane >> 4;
    const int swz  = (l15 >> 1) & 3;
    const int aoff = l15 * BK + (quad ^ swz) * 8;

    const int rA = tid >> 2;             // 0..127
    const int q8 = tid & 3;
    const float* xrow = x + (size_t)(m0 + rA) * D_DIM + q8 * 8;
    const int awo = rA * BK + ((q8 ^ ((rA >> 1) & 3)) * 8);   // XOR slot swizzle

    // per-lane B-frag base; + tIdx*16384 + jn*512 (bf16 units) per step
    const bf16* gBf = Wf + ((size_t)(((n0 + wn) >> 4) * 64 + lane)) * 8;

    bf16* const AsArr[4] = {As0, As1, As2, As3};

    f32x4 acc[4][4] = {};
    bf16x8 brA[4], brB[4];   // B-frag double buffer (parity = t&1)
    uint32_t vpk[2][4][8];   // [chunk parity][channel-pair][element]
    float xe[8];

    auto write_pack = [&](bf16* slab, const uint32_t (&P)[4][8], int j) {
        const int pr = j >> 1;
        uint32_t o[4];
#pragma unroll
        for (int m = 0; m < 4; m++) {
            uint32_t lo = P[pr][2*m], hi = P[pr][2*m+1];
            o[m] = (j & 1) ? ((lo >> 16) | (hi & 0xFFFF0000u))
                           : ((lo & 0xFFFFu) | (hi << 16));
        }
        *(uint4*)(slab + awo) = *(const uint4*)o;
    };
    auto write_silu = [&](bf16* slab) {
        float sl[8];
#pragma unroll
        for (int e = 0; e < 8; e++)
            sl[e] = xe[e] * __builtin_amdgcn_rcpf(1.0f + __expf(-xe[e]));
        uint32_t o[4] = {pk2(sl[0],sl[1]), pk2(sl[2],sl[3]),
                         pk2(sl[4],sl[5]), pk2(sl[6],sl[7])};
        *(uint4*)(slab + awo) = *(const uint4*)o;
    };

    // ---- prologue: B-frag t0 -> brA; x chunk0; features c0; As slabs 0,1 ----
    {
#pragma unroll
        for (int jn = 0; jn < 4; jn++)          // tIdx = 0
            brA[jn] = *(const bf16x8*)(gBf + jn * 512);
        float4 a = *(const float4*)xrow;
        float4 b = *(const float4*)(xrow + 4);
        xe[0]=a.x; xe[1]=a.y; xe[2]=a.z; xe[3]=a.w;
        xe[4]=b.x; xe[5]=b.y; xe[6]=b.z; xe[7]=b.w;
#pragma unroll
        for (int e = 0; e < 8; e++) {
            uint32_t o4[4];
            spline_pairs(xe[e], o4);
            vpk[0][0][e]=o4[0]; vpk[0][1][e]=o4[1];
            vpk[0][2][e]=o4[2]; vpk[0][3][e]=o4[3];
        }
        write_silu(As0);              // step 0 = (c0, f0) silu
        write_pack(As1, vpk[0], 0);   // step 1 = (c0, f1) spline channel 0
        BARA;
    }

    auto step_body = [&](auto c4v, auto fv, int c) {
        constexpr int C4 = decltype(c4v)::value;   // c mod 4
        constexpr int F  = decltype(fv)::value;    // 0..8
        constexpr int PC = C4 & 1;
        constexpr int TP = (C4 + F) & 1;           // t&1: breg parity
        constexpr int AR = (C4 + F) & 3;           // As read  = t mod 4
        constexpr int AW = (C4 + F + 2) & 3;       // As write = (t+2) mod 4

        // (0) x prefetch for chunk c+1
        if (F == 0 && c < 15) {
            float4 a = *(const float4*)(xrow + (c + 1) * 32);
            float4 b = *(const float4*)(xrow + (c + 1) * 32 + 4);
            xe[0]=a.x; xe[1]=a.y; xe[2]=a.z; xe[3]=a.w;
            xe[4]=b.x; xe[5]=b.y; xe[6]=b.z; xe[7]=b.w;
        }
        // (1) B-frag register loads for step t+1 (issue early, use next step)
        if (!(c == 15 && F == 8)) {
            const int tN = (F < 8) ? ((F + 1) * 16 + c) : (c + 1);
            const bf16* src = gBf + (size_t)tN * 16384;
            if constexpr (TP == 0) {
#pragma unroll
                for (int jn = 0; jn < 4; jn++)
                    brB[jn] = *(const bf16x8*)(src + jn * 512);
            } else {
#pragma unroll
                for (int jn = 0; jn < 4; jn++)
                    brA[jn] = *(const bf16x8*)(src + jn * 512);
            }
        }
        // (2) A-frag ds_reads
        bf16x8 af[4];
#pragma unroll
        for (int tt = 0; tt < 4; tt++)
            af[tt] = *(const bf16x8*)(AsArr[AR] + (wm + tt * 16) * BK + aoff);

        // (3) pipelined featurize: elem F-1 of chunk c+1
        if (F >= 1 && c < 15) {
            uint32_t o4[4];
            spline_pairs(xe[F - 1], o4);
            vpk[PC ^ 1][0][F-1]=o4[0]; vpk[PC ^ 1][1][F-1]=o4[1];
            vpk[PC ^ 1][2][F-1]=o4[2]; vpk[PC ^ 1][3][F-1]=o4[3];
        }
        // (4) As write for step t+2
        if constexpr (F <= 6) {
            write_pack(AsArr[AW], vpk[PC], F + 1);          // (c, F+2) -> j=F+1
        } else if constexpr (F == 7) {
            if (c < 15) write_silu(AsArr[AW]);              // (c+1, 0) silu
        } else {
            if (c < 15) write_pack(AsArr[AW], vpk[PC ^ 1], 0); // (c+1, 1) -> j=0
        }

        // (5) MFMA cluster, priority-boosted
        __builtin_amdgcn_s_setprio(1);
#pragma unroll
        for (int im = 0; im < 4; im++)
#pragma unroll
            for (int jn = 0; jn < 4; jn++)
                acc[im][jn] = __builtin_amdgcn_mfma_f32_16x16x32_bf16(
                    af[im], (TP == 0) ? brA[jn] : brB[jn], acc[im][jn], 0, 0, 0);
        __builtin_amdgcn_s_setprio(0);

        // (6) barrier at interval (odd-t) ends; protects As only (lgkm drain).
        if constexpr (TP == 1) {
            if (!(c == 15 && F == 8)) BARA;    // final step: no barrier
        }
    };

#define IC(n) std::integral_constant<int,(n)>{}
    auto chunk_body = [&](auto c4v, int c) {
        step_body(c4v, IC(0), c); step_body(c4v, IC(1), c); step_body(c4v, IC(2), c);
        step_body(c4v, IC(3), c); step_body(c4v, IC(4), c); step_body(c4v, IC(5), c);
        step_body(c4v, IC(6), c); step_body(c4v, IC(7), c); step_body(c4v, IC(8), c);
    };

    for (int cc = 0; cc < 16; cc += 4) {
        chunk_body(IC(0), cc);
        chunk_body(IC(1), cc + 1);
        chunk_body(IC(2), cc + 2);
        chunk_body(IC(3), cc + 3);
    }
#undef IC

    // C/D layout: col = lane&15, row = quad*4 + reg   [measured m89/m91]
#pragma unroll
    for (int im = 0; im < 4; im++) {
        const int rbase = m0 + wm + im * 16 + quad * 4;
#pragma unroll
        for (int jn = 0; jn < 4; jn++) {
            const int col = n0 + wn + jn * 16 + l15;
#pragma unroll
            for (int rr = 0; rr < 4; rr++)
                C[(size_t)(rbase + rr) * O_DIM + col] = acc[im][jn][rr];
        }
    }
}

extern "C" void kernel_launch(void* const* d_in, const int* in_sizes, int n_in,
                              void* d_out, int out_size, void* d_ws, size_t ws_size,
                              hipStream_t stream) {
    const float* x  = (const float*)d_in[0];
    const float* bw = (const float*)d_in[1];
    const float* sw = (const float*)d_in[2];
    float* out = (float*)d_out;

    const size_t Wbytes = (size_t)144 * 32 * 64 * 8 * sizeof(bf16);  // 4.7 MB
    if (ws_size < Wbytes) return;
    bf16* W = (bf16*)d_ws;

    pack_w_kernel<<<(O_DIM * 64 + 255) / 256, 256, 0, stream>>>(bw, sw, W);
    gemm_fused_kernel<<<dim3(B_ROWS / BM * (O_DIM / BN)), dim3(512), 0, stream>>>(x, W, out);
}

// Round 6
// 152.810 us; speedup vs baseline: 1.2562x; 1.0988x over previous
//
#include <hip/hip_runtime.h>
#include <cstdint>
#include <cstddef>
#include <type_traits>

#define B_ROWS 16384
#define D_DIM  512
#define O_DIM  512
#define BM 64
#define BN 512
#define BK 32
// W repacked fragment-major: Wf[tIdx=f*16+c][cb=o/16][lane][8 bf16]
// (tIdx<144, cb<32, lane<64). A wave's B-fragment (16 cols x 8 k) is the
// contiguous 1KB chunk at ((tIdx*32+cb)*64)*8 -- one coalesced
// global_load_dwordx4 per lane, straight to VGPR.

typedef __bf16 bf16;
typedef __attribute__((ext_vector_type(8))) bf16  bf16x8;
typedef __attribute__((ext_vector_type(4))) float f32x4;

__device__ __forceinline__ uint32_t pk2(float a, float b) {
    uint16_t ua = __builtin_bit_cast(uint16_t, (__bf16)a);
    uint16_t ub = __builtin_bit_cast(uint16_t, (__bf16)b);
    return (uint32_t)ua | ((uint32_t)ub << 16);
}

// Spline channels b0..b7 for one element as 4 packed bf16 pair-regs.
__device__ __forceinline__ void spline_pairs(float xv, uint32_t out[4]) {
    float xn = fminf(fmaxf(xv, -2.0f), 2.0f);
    float t  = (xn + 3.2f) * 2.5f;        // in [3,13]
    int   j0 = (int)t;                    // t>0 so trunc==floor
    float u  = t - (float)j0;
    float u2 = u * u, u3 = u2 * u, omu = 1.0f - u;
    const float s6 = 1.0f / 6.0f;
    float w0 = omu * omu * omu * s6;
    float w1 = (3.0f * u3 - 6.0f * u2 + 4.0f) * s6;
    float w2 = (-3.0f * u3 + 3.0f * u2 + 3.0f * u + 1.0f) * s6;
    float w3 = u3 * s6;
    uint64_t W64 = ((uint64_t)pk2(w2, w3) << 32) | pk2(w0, w1);
    int sh = (j0 - 3) * 16;               // 0..160
    uint64_t lo = W64 << (sh & 63);
    uint64_t hi = W64 >> ((64 - sh) & 63);
    uint32_t lo_lo = (uint32_t)lo, lo_hi = (uint32_t)(lo >> 32);
    uint32_t hi_lo = (uint32_t)hi, hi_hi = (uint32_t)(hi >> 32);
    bool lt64 = sh < 64, eq0 = (sh == 0), lt128 = sh < 128;
    out[0] = lt64 ? lo_lo : 0u;
    out[1] = lt64 ? lo_hi : 0u;
    out[2] = lt64 ? (eq0 ? 0u : hi_lo) : (lt128 ? lo_lo : 0u);
    out[3] = lt64 ? (eq0 ? 0u : hi_hi) : (lt128 ? lo_hi : 0u);
}

// base_weight[O,D] + spline_weight[O,D,8] fp32 -> frag-major Wf (bf16).
__global__ void pack_w_kernel(const float* __restrict__ bw,
                              const float* __restrict__ sw,
                              bf16* __restrict__ W) {
    int idx = blockIdx.x * blockDim.x + threadIdx.x;   // over O*64
    if (idx >= O_DIM * 64) return;
    int o  = idx >> 6;
    int i0 = (idx & 63) * 8;

    bf16 ob[9][8];
    const float* bwp = bw + (size_t)o * D_DIM + i0;
#pragma unroll
    for (int e = 0; e < 8; e++) {
        ob[0][e] = (bf16)bwp[e];
        const float* sp = sw + ((size_t)o * D_DIM + i0 + e) * 8;
#pragma unroll
        for (int c = 0; c < 8; c++)
            ob[c + 1][e] = (bf16)sp[c];
    }
    const int c   = i0 >> 5;              // k-chunk within channel
    const int sub = (i0 & 31) >> 3;       // quad (k-block within chunk)
    const int cb  = o >> 4;
    const int ln  = (o & 15) + sub * 16;
#pragma unroll
    for (int f = 0; f < 9; f++) {
        size_t off = ((size_t)((f * 16 + c) * 32 + cb) * 64 + ln) * 8;
        *(bf16x8*)(W + off) = *(const bf16x8*)ob[f];
    }
}

// As-only barrier: drain LDS ops, then barrier (B lives in VGPRs).
#define BARA asm volatile("s_waitcnt lgkmcnt(0)\n\ts_barrier" ::: "memory")

// R14 (resubmit; R5 bench was an infra failure, kernel re-audited clean):
// BM=64 x BN=512 (grid 256 = 1 block/CU, 8 waves each a 64x64 n-slice of
// the SAME 64 rows). Fixes R13's two problems at once:
//  - featurize duplication gone (each x-row featurized once globally, was 2x
//    with BN=256): per-thread featurize work halves (4 elems/chunk),
//  - vpk shrinks 64->32 VGPR -> fits the 128-reg allocation, no hot spill
//    (R13: VGPR=128 + 5.6MB scratch writes).
// Structure otherwise R13: B-frags L2->VGPR from frag-major Wf, dbuf dist 1;
// As 4 slabs (4KB), write dist 2; barrier every 2 steps, lgkm-only.
// MFMA operand bits and accumulation order unchanged -> same absmax.
__global__ __launch_bounds__(512, 2)
void gemm_fused_kernel(const float* __restrict__ x, const bf16* __restrict__ Wf,
                       float* __restrict__ C) {
    __shared__ __align__(16) bf16 As0[BM * BK], As1[BM * BK], As2[BM * BK], As3[BM * BK];

    const int tid  = threadIdx.x;
    const int bid  = blockIdx.x;
    const int m0   = bid * BM;
    const int wave = tid >> 6;
    const int lane = tid & 63;
    const int wn   = wave * 64;          // 8 waves cover N=512
    const int l15  = lane & 15;
    const int quad = lane >> 4;
    const int swz  = (l15 >> 1) & 3;
    const int aoff = l15 * BK + (quad ^ swz) * 8;

    // featurize: thread owns (row rA, 4 i's at octant q4 of the 32-chunk)
    const int rA = tid >> 3;             // 0..63
    const int q4 = tid & 7;
    const float* xrow = x + (size_t)(m0 + rA) * D_DIM + q4 * 4;
    // 8B write at 16B-slot (q4>>1) XOR-swizzled to match aoff's read swizzle
    const int awo = rA * BK + (((q4 >> 1) ^ ((rA >> 1) & 3)) * 8) + (q4 & 1) * 4;

    // per-lane B-frag base; + tIdx*16384 + jn*512 (bf16 units) per step
    const bf16* gBf = Wf + ((size_t)((wn >> 4) * 64 + lane)) * 8;

    bf16* const AsArr[4] = {As0, As1, As2, As3};

    f32x4 acc[4][4] = {};
    bf16x8 brA[4], brB[4];   // B-frag double buffer (parity = t&1)
    uint32_t vpk[2][4][4];   // [chunk parity][channel-pair][element 0..3]
    float xe[4];

    // pack spline channel j (0..7) of this thread's 4 elems into 8B
    auto write_pack = [&](bf16* slab, const uint32_t (&P)[4][4], int j) {
        const int pr = j >> 1;
        uint32_t o[2];
#pragma unroll
        for (int m = 0; m < 2; m++) {
            uint32_t lo = P[pr][2*m], hi = P[pr][2*m+1];
            o[m] = (j & 1) ? ((lo >> 16) | (hi & 0xFFFF0000u))
                           : ((lo & 0xFFFFu) | (hi << 16));
        }
        *(uint2*)(slab + awo) = *(const uint2*)o;
    };
    auto write_silu = [&](bf16* slab) {
        float sl[4];
#pragma unroll
        for (int e = 0; e < 4; e++)
            sl[e] = xe[e] * __builtin_amdgcn_rcpf(1.0f + __expf(-xe[e]));
        uint32_t o[2] = {pk2(sl[0],sl[1]), pk2(sl[2],sl[3])};
        *(uint2*)(slab + awo) = *(const uint2*)o;
    };

    // ---- prologue: B-frag t0 -> brA; x chunk0; features c0; As slabs 0,1 ----
    {
#pragma unroll
        for (int jn = 0; jn < 4; jn++)          // tIdx = 0
            brA[jn] = *(const bf16x8*)(gBf + jn * 512);
        float4 a = *(const float4*)xrow;
        xe[0]=a.x; xe[1]=a.y; xe[2]=a.z; xe[3]=a.w;
#pragma unroll
        for (int e = 0; e < 4; e++) {
            uint32_t o4[4];
            spline_pairs(xe[e], o4);
            vpk[0][0][e]=o4[0]; vpk[0][1][e]=o4[1];
            vpk[0][2][e]=o4[2]; vpk[0][3][e]=o4[3];
        }
        write_silu(As0);              // step 0 = (c0, f0) silu
        write_pack(As1, vpk[0], 0);   // step 1 = (c0, f1) spline channel 0
        BARA;
    }

    auto step_body = [&](auto c4v, auto fv, int c) {
        constexpr int C4 = decltype(c4v)::value;   // c mod 4
        constexpr int F  = decltype(fv)::value;    // 0..8
        constexpr int PC = C4 & 1;
        constexpr int TP = (C4 + F) & 1;           // t&1: breg parity
        constexpr int AR = (C4 + F) & 3;           // As read  = t mod 4
        constexpr int AW = (C4 + F + 2) & 3;       // As write = (t+2) mod 4

        // (0) x prefetch for chunk c+1
        if (F == 0 && c < 15) {
            float4 a = *(const float4*)(xrow + (c + 1) * 32);
            xe[0]=a.x; xe[1]=a.y; xe[2]=a.z; xe[3]=a.w;
        }
        // (1) B-frag register loads for step t+1 (issue early, use next step)
        if (!(c == 15 && F == 8)) {
            const int tN = (F < 8) ? ((F + 1) * 16 + c) : (c + 1);
            const bf16* src = gBf + (size_t)tN * 16384;
            if constexpr (TP == 0) {
#pragma unroll
                for (int jn = 0; jn < 4; jn++)
                    brB[jn] = *(const bf16x8*)(src + jn * 512);
            } else {
#pragma unroll
                for (int jn = 0; jn < 4; jn++)
                    brA[jn] = *(const bf16x8*)(src + jn * 512);
            }
        }
        // (2) A-frag ds_reads (all waves read the same 64 rows)
        bf16x8 af[4];
#pragma unroll
        for (int tt = 0; tt < 4; tt++)
            af[tt] = *(const bf16x8*)(AsArr[AR] + tt * 16 * BK + aoff);

        // (3) pipelined featurize: elem F-1 of chunk c+1 (4 elems, F=1..4)
        if constexpr (F >= 1 && F <= 4) {
            if (c < 15) {
                uint32_t o4[4];
                spline_pairs(xe[F - 1], o4);
                vpk[PC ^ 1][0][F-1]=o4[0]; vpk[PC ^ 1][1][F-1]=o4[1];
                vpk[PC ^ 1][2][F-1]=o4[2]; vpk[PC ^ 1][3][F-1]=o4[3];
            }
        }
        // (4) As write for step t+2
        if constexpr (F <= 6) {
            write_pack(AsArr[AW], vpk[PC], F + 1);          // (c, F+2) -> j=F+1
        } else if constexpr (F == 7) {
            if (c < 15) write_silu(AsArr[AW]);              // (c+1, 0) silu
        } else {
            if (c < 15) write_pack(AsArr[AW], vpk[PC ^ 1], 0); // (c+1, 1) -> j=0
        }

        // (5) MFMA cluster, priority-boosted
        __builtin_amdgcn_s_setprio(1);
#pragma unroll
        for (int im = 0; im < 4; im++)
#pragma unroll
            for (int jn = 0; jn < 4; jn++)
                acc[im][jn] = __builtin_amdgcn_mfma_f32_16x16x32_bf16(
                    af[im], (TP == 0) ? brA[jn] : brB[jn], acc[im][jn], 0, 0, 0);
        __builtin_amdgcn_s_setprio(0);

        // (6) barrier at interval (odd-t) ends; protects As only (lgkm drain).
        if constexpr (TP == 1) {
            if (!(c == 15 && F == 8)) BARA;    // final step: no barrier
        }
    };

#define IC(n) std::integral_constant<int,(n)>{}
    auto chunk_body = [&](auto c4v, int c) {
        step_body(c4v, IC(0), c); step_body(c4v, IC(1), c); step_body(c4v, IC(2), c);
        step_body(c4v, IC(3), c); step_body(c4v, IC(4), c); step_body(c4v, IC(5), c);
        step_body(c4v, IC(6), c); step_body(c4v, IC(7), c); step_body(c4v, IC(8), c);
    };

    for (int cc = 0; cc < 16; cc += 4) {
        chunk_body(IC(0), cc);
        chunk_body(IC(1), cc + 1);
        chunk_body(IC(2), cc + 2);
        chunk_body(IC(3), cc + 3);
    }
#undef IC

    // C/D layout: col = lane&15, row = quad*4 + reg   [measured m89/m91]
#pragma unroll
    for (int im = 0; im < 4; im++) {
        const int rbase = m0 + im * 16 + quad * 4;
#pragma unroll
        for (int jn = 0; jn < 4; jn++) {
            const int col = wn + jn * 16 + l15;
#pragma unroll
            for (int rr = 0; rr < 4; rr++)
                C[(size_t)(rbase + rr) * O_DIM + col] = acc[im][jn][rr];
        }
    }
}

extern "C" void kernel_launch(void* const* d_in, const int* in_sizes, int n_in,
                              void* d_out, int out_size, void* d_ws, size_t ws_size,
                              hipStream_t stream) {
    const float* x  = (const float*)d_in[0];
    const float* bw = (const float*)d_in[1];
    const float* sw = (const float*)d_in[2];
    float* out = (float*)d_out;

    const size_t Wbytes = (size_t)144 * 32 * 64 * 8 * sizeof(bf16);  // 4.7 MB
    if (ws_size < Wbytes) return;
    bf16* W = (bf16*)d_ws;

    pack_w_kernel<<<(O_DIM * 64 + 255) / 256, 256, 0, stream>>>(bw, sw, W);
    gemm_fused_kernel<<<dim3(B_ROWS / BM), dim3(512), 0, stream>>>(x, W, out);
}